// Round 3
// baseline (86.157 us; speedup 1.0000x reference)
//
#include <hip/hip_runtime.h>
#include <math.h>

// KAN edge function: out = w_base * silu(x) + w_spline * spline(x)
// spline(x) = sum_k B_k,3(x) * c_k with clamped-uniform cubic B-spline basis,
// knots = linspace(-5,5,64) with 3-fold end repeats (70 knots, 66 bases).
// Only 4 bases are nonzero per x -> local de Boor (NURBS Book A2.2).

#define GRID_N   64
#define DEGREE   3
#define NBASIS   66           // GRID_N + DEGREE - 1
#define RLO     (-5.0f)
#define RHI      (5.0f)
#define HSTEP    (10.0f / 63.0f)
#define INV_H    (63.0f / 10.0f)

// Full knot vector value: T[m] = -5 + clamp(m-3, 0, 63) * h,  m in [0,69]
__device__ __forceinline__ float knotT(int m) {
    int k = m - 3;
    k = k < 0 ? 0 : (k > 63 ? 63 : k);
    return RLO + (float)k * HSTEP;
}

__device__ __forceinline__ float eval_one(float x, const float* __restrict__ c,
                                          float wb, float ws) {
    // silu
    float silu = x / (1.0f + __expf(-x));

    // locate interior interval i in [0,62]; span index j = i + DEGREE
    int i = (int)floorf((x - RLO) * INV_H);
    i = i < 0 ? 0 : (i > 62 ? 62 : i);
    int j = i + DEGREE;

    // de Boor basis evaluation (degree 3): N0..N3 = N_{j-3..j,3}(x)
    float left1  = x - knotT(j);
    float right1 = knotT(j + 1) - x;
    float left2  = x - knotT(j - 1);
    float right2 = knotT(j + 2) - x;
    float left3  = x - knotT(j - 2);
    float right3 = knotT(j + 3) - x;

    float N0 = 1.0f, N1, N2, N3;
    // d = 1
    {
        float t0 = N0 / (right1 + left1);
        N0 = right1 * t0;
        N1 = left1 * t0;
    }
    // d = 2
    {
        float t0 = N0 / (right1 + left2);
        N0 = right1 * t0;
        float saved = left2 * t0;
        float t1 = N1 / (right2 + left1);
        N1 = saved + right2 * t1;
        N2 = left1 * t1;
    }
    // d = 3
    {
        float t0 = N0 / (right1 + left3);
        N0 = right1 * t0;
        float saved = left3 * t0;
        float t1 = N1 / (right2 + left2);
        N1 = saved + right2 * t1;
        saved = left2 * t1;
        float t2 = N2 / (right3 + left1);
        N2 = saved + right3 * t2;
        N3 = left1 * t2;
    }

    float spline = N0 * c[j - 3] + N1 * c[j - 2] + N2 * c[j - 1] + N3 * c[j];

    // half-open domain: basis is 0 for x < -5 or x >= 5 (and NaN-safe: mask=0)
    float mask = (x >= RLO && x < RHI) ? 1.0f : 0.0f;
    return wb * silu + ws * (spline * mask);
}

__global__ __launch_bounds__(256) void kan_edge_kernel(
    const float* __restrict__ x,
    const float* __restrict__ w_base_p,
    const float* __restrict__ w_spline_p,
    const float* __restrict__ coeffs,
    float* __restrict__ out, int n)
{
    const float wb = w_base_p[0];
    const float ws = w_spline_p[0];

    const int nvec = n >> 2;
    const float4* __restrict__ xv = reinterpret_cast<const float4*>(x);
    float4* __restrict__ ov = reinterpret_cast<float4*>(out);

    const int stride = gridDim.x * blockDim.x;
    for (int idx = blockIdx.x * blockDim.x + threadIdx.x; idx < nvec; idx += stride) {
        float4 v = xv[idx];
        float4 o;
        o.x = eval_one(v.x, coeffs, wb, ws);
        o.y = eval_one(v.y, coeffs, wb, ws);
        o.z = eval_one(v.z, coeffs, wb, ws);
        o.w = eval_one(v.w, coeffs, wb, ws);
        ov[idx] = o;
    }
    // scalar tail (n not multiple of 4)
    const int tail = nvec << 2;
    for (int idx = tail + blockIdx.x * blockDim.x + threadIdx.x; idx < n; idx += stride) {
        out[idx] = eval_one(x[idx], coeffs, wb, ws);
    }
}

extern "C" void kernel_launch(void* const* d_in, const int* in_sizes, int n_in,
                              void* d_out, int out_size, void* d_ws, size_t ws_size,
                              hipStream_t stream)
{
    const float* x        = (const float*)d_in[0];
    const float* w_base   = (const float*)d_in[1];
    const float* w_spline = (const float*)d_in[2];
    const float* coeffs   = (const float*)d_in[3];
    float* out = (float*)d_out;

    const int n = in_sizes[0];
    const int nvec = n >> 2;
    int blocks = (nvec + 255) / 256;
    if (blocks > 2048) blocks = 2048;
    if (blocks < 1) blocks = 1;

    kan_edge_kernel<<<blocks, 256, 0, stream>>>(x, w_base, w_spline, coeffs, out, n);
}

// Round 4
// 86.082 us; speedup vs baseline: 1.0009x; 1.0009x over previous
//
#include <hip/hip_runtime.h>
#include <math.h>

// KAN edge function: out = w_base * silu(x) + w_spline * spline(x)
// Cubic clamped-uniform B-spline, 66 bases; only 4 nonzero per x ->
// local de Boor (NURBS Book A2.2) with in-register knots.
// R4 change vs R3: __fdividef fast division (denominators are knot diffs
// >= h > 0, well-conditioned), exact-cover grid (no grid-stride loop),
// truncation instead of floorf.

#define RLO     (-5.0f)
#define RHI      (5.0f)
#define HSTEP    (10.0f / 63.0f)
#define INV_H    (63.0f / 10.0f)

// Full knot vector value: T[m] = -5 + clamp(m-3, 0, 63) * h,  m in [0,69]
__device__ __forceinline__ float knotT(int m) {
    int k = m - 3;
    k = k < 0 ? 0 : (k > 63 ? 63 : k);
    return RLO + (float)k * HSTEP;
}

__device__ __forceinline__ float eval_one(float x, const float* __restrict__ c,
                                          float wb, float ws) {
    // silu
    float silu = x / (1.0f + __expf(-x));

    // interior interval i in [0,62]; span index j = i + 3
    // (truncation == floor for x >= RLO; x < RLO clamps to 0 regardless)
    int i = (int)((x - RLO) * INV_H);
    i = i < 0 ? 0 : (i > 62 ? 62 : i);
    int j = i + 3;

    float left1  = x - knotT(j);
    float right1 = knotT(j + 1) - x;
    float left2  = x - knotT(j - 1);
    float right2 = knotT(j + 2) - x;
    float left3  = x - knotT(j - 2);
    float right3 = knotT(j + 3) - x;

    // de Boor degree-3 basis; all denominators are in [h, 3h], fast rcp ok
    float N0 = 1.0f, N1, N2, N3;
    {
        float t0 = __fdividef(N0, right1 + left1);
        N0 = right1 * t0;
        N1 = left1 * t0;
    }
    {
        float t0 = __fdividef(N0, right1 + left2);
        N0 = right1 * t0;
        float saved = left2 * t0;
        float t1 = __fdividef(N1, right2 + left1);
        N1 = saved + right2 * t1;
        N2 = left1 * t1;
    }
    {
        float t0 = __fdividef(N0, right1 + left3);
        N0 = right1 * t0;
        float saved = left3 * t0;
        float t1 = __fdividef(N1, right2 + left2);
        N1 = saved + right2 * t1;
        saved = left2 * t1;
        float t2 = __fdividef(N2, right3 + left1);
        N2 = saved + right3 * t2;
        N3 = left1 * t2;
    }

    float spline = N0 * c[j - 3] + N1 * c[j - 2] + N2 * c[j - 1] + N3 * c[j];

    // half-open domain: basis is 0 for x < -5 or x >= 5
    float mask = (x >= RLO && x < RHI) ? 1.0f : 0.0f;
    return wb * silu + ws * (spline * mask);
}

__global__ __launch_bounds__(256) void kan_edge_kernel(
    const float* __restrict__ x,
    const float* __restrict__ w_base_p,
    const float* __restrict__ w_spline_p,
    const float* __restrict__ coeffs,
    float* __restrict__ out, int n)
{
    const float wb = w_base_p[0];
    const float ws = w_spline_p[0];

    const int nvec = n >> 2;
    const float4* __restrict__ xv = reinterpret_cast<const float4*>(x);
    float4* __restrict__ ov = reinterpret_cast<float4*>(out);

    int idx = blockIdx.x * blockDim.x + threadIdx.x;
    if (idx < nvec) {
        float4 v = xv[idx];
        float4 o;
        o.x = eval_one(v.x, coeffs, wb, ws);
        o.y = eval_one(v.y, coeffs, wb, ws);
        o.z = eval_one(v.z, coeffs, wb, ws);
        o.w = eval_one(v.w, coeffs, wb, ws);
        ov[idx] = o;
    }
    // scalar tail (n not multiple of 4)
    const int tail = nvec << 2;
    for (int k = tail + idx; k < n; k += gridDim.x * blockDim.x) {
        out[k] = eval_one(x[k], coeffs, wb, ws);
    }
}

extern "C" void kernel_launch(void* const* d_in, const int* in_sizes, int n_in,
                              void* d_out, int out_size, void* d_ws, size_t ws_size,
                              hipStream_t stream)
{
    const float* x        = (const float*)d_in[0];
    const float* w_base   = (const float*)d_in[1];
    const float* w_spline = (const float*)d_in[2];
    const float* coeffs   = (const float*)d_in[3];
    float* out = (float*)d_out;

    const int n = in_sizes[0];
    const int nvec = n >> 2;
    int blocks = (nvec + 255) / 256;   // exact cover: 4096 blocks for 2048^2
    if (blocks < 1) blocks = 1;

    kan_edge_kernel<<<blocks, 256, 0, stream>>>(x, w_base, w_spline, coeffs, out, n);
}